// Round 9
// baseline (595.589 us; speedup 1.0000x reference)
//
#include <hip/hip_runtime.h>
#include <math.h>

#define NND 50000      // nodes
#define NE0 800000     // raw edges
#define NET 850000     // edges + self loops
#define SCAN_B 196     // ceil(NND/256)
#define NBUK 782       // ceil(NND/64) buckets for CSR fill

using short8  = __attribute__((ext_vector_type(8))) short;
using ushort8 = __attribute__((ext_vector_type(8))) unsigned short;
using f32x4   = __attribute__((ext_vector_type(4))) float;

__device__ __forceinline__ float lrelu(float v) { return fmaxf(v, 0.2f * v); }

__device__ __forceinline__ unsigned short f2bf(float f) {
    unsigned int u = __float_as_uint(f);
    u = (u + 0x7fff + ((u >> 16) & 1)) >> 16;   // RNE
    return (unsigned short)u;
}
__device__ __forceinline__ float2 bf2x2(unsigned int u) {
    float2 r;
    r.x = __uint_as_float(u << 16);
    r.y = __uint_as_float(u & 0xffff0000u);
    return r;
}
__device__ __forceinline__ unsigned int packbf(float x, float y) {
    return (unsigned int)f2bf(x) | ((unsigned int)f2bf(y) << 16);
}

// butterfly-add via DPP (VALU pipe): 0xB1 xor1 | 0x4E xor2 | 0x141 xor4-when-
// uniform-in-4 | 0x140 xor8-when-uniform-in-8
template <int CTRL>
__device__ __forceinline__ float dpp_add(float v) {
    int j = __builtin_amdgcn_update_dpp(0, __float_as_int(v), CTRL, 0xf, 0xf, true);
    return v + __int_as_float(j);
}

// ---- weight prep, both layers in one launch: [128][N] f32 -> [N][128] bf16 ----
__global__ __launch_bounds__(256) void wt_prep_all(
    const float* __restrict__ A0, const float* __restrict__ A1, const float* __restrict__ A2,
    const float* __restrict__ B0, const float* __restrict__ B1, const float* __restrict__ B2,
    unsigned short* __restrict__ T1, unsigned short* __restrict__ T2) {
    const int L1 = 3 * 128 * 128;            // 49152
    const int L2 = 3 * 64 * 128;             // 24576
    int idx = blockIdx.x * blockDim.x + threadIdx.x;
    if (idx < L1) {
        int which = idx / 16384, rem = idx - which * 16384;
        int k = rem >> 7, n = rem & 127;
        const float* S = which == 0 ? A0 : (which == 1 ? A1 : A2);
        T1[which * 16384 + n * 128 + k] = f2bf(S[rem]);
    } else if (idx < L1 + L2) {
        int idx2 = idx - L1;
        int which = idx2 / 8192, rem = idx2 - which * 8192;
        int k = rem >> 6, n = rem & 63;
        const float* S = which == 0 ? B0 : (which == 1 ? B1 : B2);
        T2[which * 8192 + n * 128 + k] = f2bf(S[rem]);
    }
}

// ---- MFMA GEMM trio: C0=A@B0 (bf16), C1=A@B1 (bf16), C2=A@B2+bias2 ----
template <int BN, bool LN, bool OUTBF>
__global__ __launch_bounds__(256) void gemm3_mfma(
    const void* __restrict__ Av,
    const unsigned short* __restrict__ Bt0, const unsigned short* __restrict__ Bt1,
    const unsigned short* __restrict__ Bt2, const float* __restrict__ bias2,
    unsigned short* __restrict__ C0, unsigned short* __restrict__ C1,
    unsigned short* __restrict__ C2b, float* __restrict__ C2f,
    const float* __restrict__ musig, const float* __restrict__ lnw,
    const float* __restrict__ lnb, int M) {
    __shared__ __align__(16) unsigned short As[64 * 128];   // bf16, XOR-swizzled
    const int tid = threadIdx.x;
    const int m0 = blockIdx.x * 64;

    float mu = 0.f, rinv = 1.f;
    if constexpr (LN) { mu = musig[0]; rinv = musig[1]; }

    {
        const int row = tid >> 2, qc = tid & 3;
        const int gm = m0 + row;
#pragma unroll
        for (int i = 0; i < 4; i++) {
            int k0 = qc * 32 + i * 8;
            float v[8];
            if constexpr (LN) {
                const unsigned short* A = (const unsigned short*)Av;
                if (gm < M) {
                    ushort8 us = *(const ushort8*)(A + (size_t)gm * 128 + k0);
#pragma unroll
                    for (int j = 0; j < 8; j++) v[j] = __uint_as_float((unsigned int)us[j] << 16);
                } else {
#pragma unroll
                    for (int j = 0; j < 8; j++) v[j] = 0.f;
                }
                float4 w0 = *(const float4*)(lnw + k0);
                float4 w1 = *(const float4*)(lnw + k0 + 4);
                float4 b0 = *(const float4*)(lnb + k0);
                float4 b1 = *(const float4*)(lnb + k0 + 4);
                float wv[8] = {w0.x, w0.y, w0.z, w0.w, w1.x, w1.y, w1.z, w1.w};
                float bv[8] = {b0.x, b0.y, b0.z, b0.w, b1.x, b1.y, b1.z, b1.w};
#pragma unroll
                for (int j = 0; j < 8; j++) {
                    float t = wv[j] * (v[j] - mu) * rinv + bv[j];
                    v[j] = t > 0.f ? t : __expf(t) - 1.f;
                }
            } else {
                const float* A = (const float*)Av;
                if (gm < M) {
                    float4 a0 = *(const float4*)(A + (size_t)gm * 128 + k0);
                    float4 a1 = *(const float4*)(A + (size_t)gm * 128 + k0 + 4);
                    v[0] = a0.x; v[1] = a0.y; v[2] = a0.z; v[3] = a0.w;
                    v[4] = a1.x; v[5] = a1.y; v[6] = a1.z; v[7] = a1.w;
                } else {
#pragma unroll
                    for (int j = 0; j < 8; j++) v[j] = 0.f;
                }
            }
            short8 pk;
#pragma unroll
            for (int j = 0; j < 8; j++) pk[j] = (short)f2bf(v[j]);
            *(short8*)&As[row * 128 + (k0 ^ ((row & 7) << 3))] = pk;
        }
    }
    __syncthreads();

    const int lane = tid & 63;
    const int wid = tid >> 6;
    const int lr = lane & 15;
    const int lk = lane >> 4;

    short8 a[4][4];
#pragma unroll
    for (int rf = 0; rf < 4; rf++) {
        int row = rf * 16 + lr;
#pragma unroll
        for (int kc = 0; kc < 4; kc++) {
            int k0 = kc * 32 + lk * 8;
            a[rf][kc] = *(short8*)&As[row * 128 + (k0 ^ ((row & 7) << 3))];
        }
    }

    constexpr int NCF = BN / 64;
    const int nbase = wid * (BN / 4);

    const unsigned short* Bts[3] = {Bt0, Bt1, Bt2};
#pragma unroll
    for (int j = 0; j < 3; j++) {
        const unsigned short* Bt = Bts[j];
        short8 b[NCF][4];
#pragma unroll
        for (int cf = 0; cf < NCF; cf++) {
            int n = nbase + cf * 16 + lr;
#pragma unroll
            for (int kc = 0; kc < 4; kc++)
                b[cf][kc] = *(const short8*)(Bt + (size_t)n * 128 + kc * 32 + lk * 8);
        }
        f32x4 acc[4][NCF];
#pragma unroll
        for (int rf = 0; rf < 4; rf++)
#pragma unroll
            for (int cf = 0; cf < NCF; cf++) acc[rf][cf] = (f32x4){0.f, 0.f, 0.f, 0.f};
#pragma unroll
        for (int kc = 0; kc < 4; kc++)
#pragma unroll
            for (int rf = 0; rf < 4; rf++)
#pragma unroll
                for (int cf = 0; cf < NCF; cf++)
                    acc[rf][cf] = __builtin_amdgcn_mfma_f32_16x16x32_bf16(
                        a[rf][kc], b[cf][kc], acc[rf][cf], 0, 0, 0);
        if (j < 2) {
            unsigned short* C = (j == 0) ? C0 : C1;
#pragma unroll
            for (int rf = 0; rf < 4; rf++)
#pragma unroll
                for (int cf = 0; cf < NCF; cf++) {
                    int col = nbase + cf * 16 + lr;
#pragma unroll
                    for (int r = 0; r < 4; r++) {
                        int row = m0 + rf * 16 + lk * 4 + r;
                        if (row < M) C[(size_t)row * BN + col] = f2bf(acc[rf][cf][r]);
                    }
                }
        } else {
#pragma unroll
            for (int rf = 0; rf < 4; rf++)
#pragma unroll
                for (int cf = 0; cf < NCF; cf++) {
                    int col = nbase + cf * 16 + lr;
                    float bb = bias2[col];
#pragma unroll
                    for (int r = 0; r < 4; r++) {
                        int row = m0 + rf * 16 + lk * 4 + r;
                        if (row < M) {
                            if constexpr (OUTBF)
                                C2b[(size_t)row * BN + col] = f2bf(acc[rf][cf][r] + bb);
                            else
                                C2f[(size_t)row * BN + col] = acc[rf][cf][r] + bb;
                        }
                    }
                }
        }
    }
}

// ---------------- CSR build: bucketed two-phase fill ----------------
// bucket = dst>>6 (64 dsts per bucket) so the final csrs writes for one
// bucket all come from ONE block (one XCD) into a ~4KB contiguous region.
__global__ __launch_bounds__(256) void bhist_k(const int* __restrict__ ei,
                                               int* __restrict__ bhist) {
    int i = blockIdx.x * blockDim.x + threadIdx.x;
    int stride = gridDim.x * blockDim.x;
    for (int e = i; e < NE0; e += stride) atomicAdd(&bhist[ei[NE0 + e] >> 6], 1);
}

__global__ __launch_bounds__(1024) void bscan_k(const int* __restrict__ bhist,
                                                int* __restrict__ bucketoff) {
    __shared__ int s[1024];
    const int t = threadIdx.x;
    int v = (t < NBUK) ? bhist[t] : 0;
    s[t] = v;
    __syncthreads();
    for (int off = 1; off < 1024; off <<= 1) {
        int x = (t >= off) ? s[t - off] : 0;
        __syncthreads();
        s[t] += x;
        __syncthreads();
    }
    if (t < NBUK) bucketoff[t] = s[t] - v;
    if (t == NBUK - 1) bucketoff[NBUK] = s[t];
}

// scatter packed (src | (dst&63)<<16) into bucket regions; fused deg count
__global__ __launch_bounds__(256) void bscatter_k(const int* __restrict__ ei,
                                                  const int* __restrict__ bucketoff,
                                                  int* __restrict__ bcur,
                                                  int* __restrict__ deg,
                                                  unsigned int* __restrict__ buck) {
    int i = blockIdx.x * blockDim.x + threadIdx.x;
    int stride = gridDim.x * blockDim.x;
    for (int e = i; e < NE0; e += stride) {
        int s = ei[e], d = ei[NE0 + e];
        atomicAdd(&deg[d], 1);
        int b = d >> 6;
        int pos = bucketoff[b] + atomicAdd(&bcur[b], 1);
        buck[pos] = (unsigned int)s | ((unsigned int)(d & 63) << 16);
    }
}

__global__ __launch_bounds__(256) void scan1(const int* __restrict__ deg,
                                             int* __restrict__ locexc,
                                             int* __restrict__ blocksum) {
    __shared__ int s[256];
    const int t = threadIdx.x;
    const int g = blockIdx.x * 256 + t;
    int v = (g < NND) ? deg[g] + 1 : 0;   // +1: implicit self-loop
    s[t] = v;
    __syncthreads();
    for (int off = 1; off < 256; off <<= 1) {
        int x = (t >= off) ? s[t - off] : 0;
        __syncthreads();
        s[t] += x;
        __syncthreads();
    }
    if (g < NND) locexc[g] = s[t] - v;
    if (t == 255) blocksum[blockIdx.x] = s[255];
}

__global__ __launch_bounds__(256) void scan2(const int* __restrict__ blocksum,
                                             int* __restrict__ blockoff,
                                             int* __restrict__ rowptr) {
    __shared__ int s[256];
    const int t = threadIdx.x;
    int v = (t < SCAN_B) ? blocksum[t] : 0;
    s[t] = v;
    __syncthreads();
    for (int off = 1; off < 256; off <<= 1) {
        int x = (t >= off) ? s[t - off] : 0;
        __syncthreads();
        s[t] += x;
        __syncthreads();
    }
    if (t < SCAN_B) blockoff[t] = s[t] - v;
    if (t == 255) rowptr[NND] = s[255];
}

__global__ __launch_bounds__(256) void scan3(const int* __restrict__ locexc,
                                             const int* __restrict__ blockoff,
                                             int* __restrict__ rowptr,
                                             int* __restrict__ csrs) {
    const int g = blockIdx.x * 256 + threadIdx.x;
    if (g < NND) {
        int rp = locexc[g] + blockoff[g >> 8];
        rowptr[g] = rp;
        csrs[rp] = g;   // self-loop first in each segment
    }
}

// per-bucket CSR fill: one block per bucket, LDS cursors for its 64 dsts
__global__ __launch_bounds__(256) void bfill_k(const unsigned int* __restrict__ buck,
                                               const int* __restrict__ bucketoff,
                                               const int* __restrict__ rowptr,
                                               int* __restrict__ csrs) {
    __shared__ int lcur[64];
    const int b = blockIdx.x;
    const int t = threadIdx.x;
    if (t < 64) {
        int d = b * 64 + t;
        lcur[t] = (d < NND) ? rowptr[d] + 1 : 0;   // +1: slot 0 is the self-loop
    }
    __syncthreads();
    const int start = bucketoff[b], end = bucketoff[b + 1];
    for (int e = start + t; e < end; e += 256) {
        unsigned int v = buck[e];
        int pos = atomicAdd(&lcur[v >> 16], 1);
        csrs[pos] = (int)(v & 0xffffu);
    }
}

// ---- fused logits + softmax aggregation, layer 1 (8 heads x 16) ----
__global__ __launch_bounds__(256) void aggr_l1(const int* __restrict__ rowptr,
                                               const int* __restrict__ csrs,
                                               const unsigned short* __restrict__ xl,
                                               const unsigned short* __restrict__ xr,
                                               const float* __restrict__ att,
                                               const float* __restrict__ b1,
                                               unsigned short* __restrict__ h,
                                               float2* __restrict__ partial) {
    const int lane = threadIdx.x & 63;
    const int wv = threadIdx.x >> 6;
    int wid = (blockIdx.x * blockDim.x + threadIdx.x) >> 6;
    const int nw = (gridDim.x * blockDim.x) >> 6;
    const int c = lane * 2;
    float2 attv = *(const float2*)(att + c);
    float2 b1v = *(const float2*)(b1 + c);
    float ts = 0.f, ts2 = 0.f;
    for (int d = wid; d < NND; d += nw) {
        int p0 = rowptr[d], p1 = rowptr[d + 1];
        float2 xrv = bf2x2(*(const unsigned int*)(xr + (size_t)d * 128 + c));
        float den0 = 0.f, den1 = 0.f, den2 = 0.f, den3 = 0.f;
        float a00 = 0.f, a01 = 0.f, a10 = 0.f, a11 = 0.f;
        float a20 = 0.f, a21 = 0.f, a30 = 0.f, a31 = 0.f;
        int i = p0;
        for (; i + 4 <= p1; i += 4) {
            int s0 = csrs[i], s1 = csrs[i + 1], s2 = csrs[i + 2], s3 = csrs[i + 3];
            float2 x0 = bf2x2(*(const unsigned int*)(xl + (size_t)s0 * 128 + c));
            float2 x1 = bf2x2(*(const unsigned int*)(xl + (size_t)s1 * 128 + c));
            float2 x2 = bf2x2(*(const unsigned int*)(xl + (size_t)s2 * 128 + c));
            float2 x3 = bf2x2(*(const unsigned int*)(xl + (size_t)s3 * 128 + c));
            float q0 = lrelu(x0.x + xrv.x) * attv.x + lrelu(x0.y + xrv.y) * attv.y;
            float q1 = lrelu(x1.x + xrv.x) * attv.x + lrelu(x1.y + xrv.y) * attv.y;
            float q2 = lrelu(x2.x + xrv.x) * attv.x + lrelu(x2.y + xrv.y) * attv.y;
            float q3 = lrelu(x3.x + xrv.x) * attv.x + lrelu(x3.y + xrv.y) * attv.y;
            q0 = dpp_add<0xB1>(q0); q0 = dpp_add<0x4E>(q0); q0 = dpp_add<0x141>(q0);
            q1 = dpp_add<0xB1>(q1); q1 = dpp_add<0x4E>(q1); q1 = dpp_add<0x141>(q1);
            q2 = dpp_add<0xB1>(q2); q2 = dpp_add<0x4E>(q2); q2 = dpp_add<0x141>(q2);
            q3 = dpp_add<0xB1>(q3); q3 = dpp_add<0x4E>(q3); q3 = dpp_add<0x141>(q3);
            float p0v = __expf(q0), p1v = __expf(q1), p2v = __expf(q2), p3v = __expf(q3);
            den0 += p0v; a00 = fmaf(p0v, x0.x, a00); a01 = fmaf(p0v, x0.y, a01);
            den1 += p1v; a10 = fmaf(p1v, x1.x, a10); a11 = fmaf(p1v, x1.y, a11);
            den2 += p2v; a20 = fmaf(p2v, x2.x, a20); a21 = fmaf(p2v, x2.y, a21);
            den3 += p3v; a30 = fmaf(p3v, x3.x, a30); a31 = fmaf(p3v, x3.y, a31);
        }
        for (; i < p1; i++) {
            int s0 = csrs[i];
            float2 x0 = bf2x2(*(const unsigned int*)(xl + (size_t)s0 * 128 + c));
            float q0 = lrelu(x0.x + xrv.x) * attv.x + lrelu(x0.y + xrv.y) * attv.y;
            q0 = dpp_add<0xB1>(q0); q0 = dpp_add<0x4E>(q0); q0 = dpp_add<0x141>(q0);
            float p0v = __expf(q0);
            den0 += p0v; a00 = fmaf(p0v, x0.x, a00); a01 = fmaf(p0v, x0.y, a01);
        }
        float den = (den0 + den1) + (den2 + den3);
        float a0 = (a00 + a10) + (a20 + a30);
        float a1 = (a01 + a11) + (a21 + a31);
        float inv = 1.f / den;
        unsigned int* hp = (unsigned int*)(h + (size_t)d * 128 + c);
        float2 hv = bf2x2(*hp);
        hv.x += a0 * inv + b1v.x;
        hv.y += a1 * inv + b1v.y;
        *hp = packbf(hv.x, hv.y);
        ts += hv.x + hv.y;
        ts2 += hv.x * hv.x + hv.y * hv.y;
    }
    __shared__ float red[8];
#pragma unroll
    for (int off = 32; off; off >>= 1) {
        ts += __shfl_down(ts, off);
        ts2 += __shfl_down(ts2, off);
    }
    if (lane == 0) { red[wv * 2] = ts; red[wv * 2 + 1] = ts2; }
    __syncthreads();
    if (threadIdx.x == 0) {
        float s = red[0] + red[2] + red[4] + red[6];
        float s2 = red[1] + red[3] + red[5] + red[7];
        partial[blockIdx.x] = make_float2(s, s2);
    }
}

__global__ __launch_bounds__(256) void ln_final2(const float2* __restrict__ part, int np,
                                                 float* __restrict__ musig) {
    double s = 0.0, s2 = 0.0;
    for (int i = threadIdx.x; i < np; i += 256) {
        float2 p = part[i];
        s += p.x;
        s2 += p.y;
    }
#pragma unroll
    for (int off = 32; off; off >>= 1) {
        s += __shfl_down(s, off);
        s2 += __shfl_down(s2, off);
    }
    __shared__ double red[8];
    const int wv = threadIdx.x >> 6;
    if ((threadIdx.x & 63) == 0) { red[wv * 2] = s; red[wv * 2 + 1] = s2; }
    __syncthreads();
    if (threadIdx.x == 0) {
        double S = red[0] + red[2] + red[4] + red[6];
        double S2 = red[1] + red[3] + red[5] + red[7];
        double inv_n = 1.0 / ((double)NND * 128.0);
        double mu = S * inv_n;
        double var = S2 * inv_n - mu * mu;
        musig[0] = (float)mu;
        musig[1] = (float)(1.0 / sqrt(var + 1e-5));
    }
}

// ---- fused logits + aggregation, layer 2 (1 head x 64) ----
__global__ __launch_bounds__(256) void aggr_l2(const int* __restrict__ rowptr,
                                               const int* __restrict__ csrs,
                                               const unsigned short* __restrict__ xl,
                                               const unsigned short* __restrict__ xr,
                                               const float* __restrict__ att,
                                               const float* __restrict__ b2,
                                               float* __restrict__ out) {
    const int hl = threadIdx.x & 31;
    int hwid = (blockIdx.x * blockDim.x + threadIdx.x) >> 5;
    const int nhw = (gridDim.x * blockDim.x) >> 5;
    const int c = hl * 2;
    float2 attv = *(const float2*)(att + c);
    float2 b2v = *(const float2*)(b2 + c);
    for (int d = hwid; d < NND; d += nhw) {
        int p0 = rowptr[d], p1 = rowptr[d + 1];
        float2 xrv = bf2x2(*(const unsigned int*)(xr + (size_t)d * 64 + c));
        float den0 = 0.f, den1 = 0.f, den2 = 0.f, den3 = 0.f;
        float a00 = 0.f, a01 = 0.f, a10 = 0.f, a11 = 0.f;
        float a20 = 0.f, a21 = 0.f, a30 = 0.f, a31 = 0.f;
        int i = p0;
        for (; i + 4 <= p1; i += 4) {
            int s0 = csrs[i], s1 = csrs[i + 1], s2 = csrs[i + 2], s3 = csrs[i + 3];
            float2 x0 = bf2x2(*(const unsigned int*)(xl + (size_t)s0 * 64 + c));
            float2 x1 = bf2x2(*(const unsigned int*)(xl + (size_t)s1 * 64 + c));
            float2 x2 = bf2x2(*(const unsigned int*)(xl + (size_t)s2 * 64 + c));
            float2 x3 = bf2x2(*(const unsigned int*)(xl + (size_t)s3 * 64 + c));
            float q0 = lrelu(x0.x + xrv.x) * attv.x + lrelu(x0.y + xrv.y) * attv.y;
            float q1 = lrelu(x1.x + xrv.x) * attv.x + lrelu(x1.y + xrv.y) * attv.y;
            float q2 = lrelu(x2.x + xrv.x) * attv.x + lrelu(x2.y + xrv.y) * attv.y;
            float q3 = lrelu(x3.x + xrv.x) * attv.x + lrelu(x3.y + xrv.y) * attv.y;
            q0 = dpp_add<0xB1>(q0); q0 = dpp_add<0x4E>(q0); q0 = dpp_add<0x141>(q0);
            q0 = dpp_add<0x140>(q0); q0 += __shfl_xor(q0, 16);
            q1 = dpp_add<0xB1>(q1); q1 = dpp_add<0x4E>(q1); q1 = dpp_add<0x141>(q1);
            q1 = dpp_add<0x140>(q1); q1 += __shfl_xor(q1, 16);
            q2 = dpp_add<0xB1>(q2); q2 = dpp_add<0x4E>(q2); q2 = dpp_add<0x141>(q2);
            q2 = dpp_add<0x140>(q2); q2 += __shfl_xor(q2, 16);
            q3 = dpp_add<0xB1>(q3); q3 = dpp_add<0x4E>(q3); q3 = dpp_add<0x141>(q3);
            q3 = dpp_add<0x140>(q3); q3 += __shfl_xor(q3, 16);
            float p0v = __expf(q0), p1v = __expf(q1), p2v = __expf(q2), p3v = __expf(q3);
            den0 += p0v; a00 = fmaf(p0v, x0.x, a00); a01 = fmaf(p0v, x0.y, a01);
            den1 += p1v; a10 = fmaf(p1v, x1.x, a10); a11 = fmaf(p1v, x1.y, a11);
            den2 += p2v; a20 = fmaf(p2v, x2.x, a20); a21 = fmaf(p2v, x2.y, a21);
            den3 += p3v; a30 = fmaf(p3v, x3.x, a30); a31 = fmaf(p3v, x3.y, a31);
        }
        for (; i < p1; i++) {
            int s0 = csrs[i];
            float2 x0 = bf2x2(*(const unsigned int*)(xl + (size_t)s0 * 64 + c));
            float q0 = lrelu(x0.x + xrv.x) * attv.x + lrelu(x0.y + xrv.y) * attv.y;
            q0 = dpp_add<0xB1>(q0); q0 = dpp_add<0x4E>(q0); q0 = dpp_add<0x141>(q0);
            q0 = dpp_add<0x140>(q0); q0 += __shfl_xor(q0, 16);
            float p0v = __expf(q0);
            den0 += p0v; a00 = fmaf(p0v, x0.x, a00); a01 = fmaf(p0v, x0.y, a01);
        }
        float den = (den0 + den1) + (den2 + den3);
        float a0 = (a00 + a10) + (a20 + a30);
        float a1 = (a01 + a11) + (a21 + a31);
        float inv = 1.f / den;
        float2 ov = *(float2*)(out + (size_t)d * 64 + c);
        ov.x += a0 * inv + b2v.x;
        ov.y += a1 * inv + b2v.y;
        *(float2*)(out + (size_t)d * 64 + c) = ov;
    }
}

extern "C" void kernel_launch(void* const* d_in, const int* in_sizes, int n_in,
                              void* d_out, int out_size, void* d_ws, size_t ws_size,
                              hipStream_t stream) {
    (void)in_sizes; (void)n_in; (void)out_size; (void)ws_size;
    const float* x    = (const float*)d_in[0];
    const int*   ei   = (const int*)d_in[1];
    const float* W1l  = (const float*)d_in[2];
    const float* W1r  = (const float*)d_in[3];
    const float* att1 = (const float*)d_in[4];
    const float* b1   = (const float*)d_in[5];
    const float* s1W  = (const float*)d_in[6];
    const float* s1b  = (const float*)d_in[7];
    const float* lnw  = (const float*)d_in[8];
    const float* lnb  = (const float*)d_in[9];
    const float* W2l  = (const float*)d_in[10];
    const float* W2r  = (const float*)d_in[11];
    const float* att2 = (const float*)d_in[12];
    const float* b2   = (const float*)d_in[13];
    const float* s2W  = (const float*)d_in[14];
    const float* s2b  = (const float*)d_in[15];
    float* out = (float*)d_out;

    char* ws = (char*)d_ws;
    size_t off = 0;
    auto alloc = [&](size_t bytes) {
        size_t o = off;
        off = (off + bytes + 255) & ~(size_t)255;
        return o;
    };
    unsigned short* xl = (unsigned short*)(ws + alloc((size_t)NND * 128 * 2));  // layer2 reuses (N x 64)
    unsigned short* xr = (unsigned short*)(ws + alloc((size_t)NND * 128 * 2));
    unsigned short* h  = (unsigned short*)(ws + alloc((size_t)NND * 128 * 2));  // bf16
    int* deg     = (int*)(ws + alloc((size_t)NND * 4));
    int* rowptr  = (int*)(ws + alloc((size_t)(NND + 1) * 4));
    int* csrs    = (int*)(ws + alloc((size_t)NET * 4));
    int* locexc  = (int*)(ws + alloc((size_t)NND * 4));
    int* blocksum= (int*)(ws + alloc((size_t)SCAN_B * 4));
    int* blockoff= (int*)(ws + alloc((size_t)SCAN_B * 4));
    int* bhist   = (int*)(ws + alloc((size_t)NBUK * 4));
    int* bucketoff=(int*)(ws + alloc((size_t)(NBUK + 1) * 4));
    int* bcur    = (int*)(ws + alloc((size_t)NBUK * 4));
    unsigned int* buck = (unsigned int*)(ws + alloc((size_t)NE0 * 4));
    unsigned short* Bt1 = (unsigned short*)(ws + alloc((size_t)3 * 128 * 128 * 2));
    unsigned short* Bt2 = (unsigned short*)(ws + alloc((size_t)3 * 64 * 128 * 2));
    float2* partial = (float2*)(ws + alloc((size_t)12500 * 8));
    float* musig = (float*)(ws + alloc(8));

    hipMemsetAsync(deg, 0, (size_t)NND * 4, stream);
    hipMemsetAsync(bhist, 0, (size_t)NBUK * 4, stream);
    hipMemsetAsync(bcur, 0, (size_t)NBUK * 4, stream);

    // CSR by dst (shared by both layers); bucketed fill for write locality
    bhist_k<<<2048, 256, 0, stream>>>(ei, bhist);
    bscan_k<<<1, 1024, 0, stream>>>(bhist, bucketoff);
    bscatter_k<<<2048, 256, 0, stream>>>(ei, bucketoff, bcur, deg, buck);
    scan1<<<SCAN_B, 256, 0, stream>>>(deg, locexc, blocksum);
    scan2<<<1, 256, 0, stream>>>(blocksum, blockoff, rowptr);
    scan3<<<SCAN_B, 256, 0, stream>>>(locexc, blockoff, rowptr, csrs);
    bfill_k<<<NBUK, 256, 0, stream>>>(buck, bucketoff, rowptr, csrs);

    // weight transpose + bf16 (both layers, one launch)
    wt_prep_all<<<288, 256, 0, stream>>>(W1l, W1r, s1W, W2l, W2r, s2W, Bt1, Bt2);

    // Layer 1: xl=x@W1l, xr=x@W1r (bf16), h=x@s1W+s1b (bf16)
    gemm3_mfma<128, false, true><<<782, 256, 0, stream>>>(
        (const void*)x, Bt1, Bt1 + 16384, Bt1 + 32768, s1b,
        xl, xr, h, nullptr, nullptr, nullptr, nullptr, NND);
    aggr_l1<<<12500, 256, 0, stream>>>(rowptr, csrs, xl, xr, att1, b1, h, partial);
    ln_final2<<<1, 256, 0, stream>>>(partial, 12500, musig);

    // Layer 2: xl2=hln@W2l, xr2=hln@W2r (bf16), out=hln@s2W+s2b (f32)
    gemm3_mfma<64, true, false><<<782, 256, 0, stream>>>(
        (const void*)h, Bt2, Bt2 + 8192, Bt2 + 16384, s2b,
        xl, xr, nullptr, out, musig, lnw, lnb, NND);
    aggr_l2<<<6250, 256, 0, stream>>>(rowptr, csrs, xl, xr, att2, b2, out);
}

// Round 10
// 248.994 us; speedup vs baseline: 2.3920x; 2.3920x over previous
//
#include <hip/hip_runtime.h>
#include <math.h>

#define NND 50000      // nodes
#define NE0 800000     // raw edges
#define NET 850000     // edges + self loops
#define SCAN_B 196     // ceil(NND/256)

using short8  = __attribute__((ext_vector_type(8))) short;
using ushort8 = __attribute__((ext_vector_type(8))) unsigned short;
using f32x4   = __attribute__((ext_vector_type(4))) float;

__device__ __forceinline__ float lrelu(float v) { return fmaxf(v, 0.2f * v); }

__device__ __forceinline__ unsigned short f2bf(float f) {
    unsigned int u = __float_as_uint(f);
    u = (u + 0x7fff + ((u >> 16) & 1)) >> 16;   // RNE
    return (unsigned short)u;
}
__device__ __forceinline__ float2 bf2x2(unsigned int u) {
    float2 r;
    r.x = __uint_as_float(u << 16);
    r.y = __uint_as_float(u & 0xffff0000u);
    return r;
}
__device__ __forceinline__ unsigned int packbf(float x, float y) {
    return (unsigned int)f2bf(x) | ((unsigned int)f2bf(y) << 16);
}

// butterfly-add via DPP (VALU pipe): 0xB1 xor1 | 0x4E xor2 | 0x141 xor4-when-
// uniform-in-4 | 0x140 xor8-when-uniform-in-8
template <int CTRL>
__device__ __forceinline__ float dpp_add(float v) {
    int j = __builtin_amdgcn_update_dpp(0, __float_as_int(v), CTRL, 0xf, 0xf, true);
    return v + __int_as_float(j);
}

// ---- weight prep, both layers in one launch: [128][N] f32 -> [N][128] bf16 ----
__global__ __launch_bounds__(256) void wt_prep_all(
    const float* __restrict__ A0, const float* __restrict__ A1, const float* __restrict__ A2,
    const float* __restrict__ B0, const float* __restrict__ B1, const float* __restrict__ B2,
    unsigned short* __restrict__ T1, unsigned short* __restrict__ T2) {
    const int L1 = 3 * 128 * 128;            // 49152
    const int L2 = 3 * 64 * 128;             // 24576
    int idx = blockIdx.x * blockDim.x + threadIdx.x;
    if (idx < L1) {
        int which = idx / 16384, rem = idx - which * 16384;
        int k = rem >> 7, n = rem & 127;
        const float* S = which == 0 ? A0 : (which == 1 ? A1 : A2);
        T1[which * 16384 + n * 128 + k] = f2bf(S[rem]);
    } else if (idx < L1 + L2) {
        int idx2 = idx - L1;
        int which = idx2 / 8192, rem = idx2 - which * 8192;
        int k = rem >> 6, n = rem & 63;
        const float* S = which == 0 ? B0 : (which == 1 ? B1 : B2);
        T2[which * 8192 + n * 128 + k] = f2bf(S[rem]);
    }
}

// ---- MFMA GEMM trio: C0=A@B0 (bf16), C1=A@B1 (bf16), C2=A@B2+bias2 ----
template <int BN, bool LN, bool OUTBF>
__global__ __launch_bounds__(256) void gemm3_mfma(
    const void* __restrict__ Av,
    const unsigned short* __restrict__ Bt0, const unsigned short* __restrict__ Bt1,
    const unsigned short* __restrict__ Bt2, const float* __restrict__ bias2,
    unsigned short* __restrict__ C0, unsigned short* __restrict__ C1,
    unsigned short* __restrict__ C2b, float* __restrict__ C2f,
    const float* __restrict__ musig, const float* __restrict__ lnw,
    const float* __restrict__ lnb, int M) {
    __shared__ __align__(16) unsigned short As[64 * 128];   // bf16, XOR-swizzled
    const int tid = threadIdx.x;
    const int m0 = blockIdx.x * 64;

    float mu = 0.f, rinv = 1.f;
    if constexpr (LN) { mu = musig[0]; rinv = musig[1]; }

    {
        const int row = tid >> 2, qc = tid & 3;
        const int gm = m0 + row;
#pragma unroll
        for (int i = 0; i < 4; i++) {
            int k0 = qc * 32 + i * 8;
            float v[8];
            if constexpr (LN) {
                const unsigned short* A = (const unsigned short*)Av;
                if (gm < M) {
                    ushort8 us = *(const ushort8*)(A + (size_t)gm * 128 + k0);
#pragma unroll
                    for (int j = 0; j < 8; j++) v[j] = __uint_as_float((unsigned int)us[j] << 16);
                } else {
#pragma unroll
                    for (int j = 0; j < 8; j++) v[j] = 0.f;
                }
                float4 w0 = *(const float4*)(lnw + k0);
                float4 w1 = *(const float4*)(lnw + k0 + 4);
                float4 b0 = *(const float4*)(lnb + k0);
                float4 b1 = *(const float4*)(lnb + k0 + 4);
                float wv[8] = {w0.x, w0.y, w0.z, w0.w, w1.x, w1.y, w1.z, w1.w};
                float bv[8] = {b0.x, b0.y, b0.z, b0.w, b1.x, b1.y, b1.z, b1.w};
#pragma unroll
                for (int j = 0; j < 8; j++) {
                    float t = wv[j] * (v[j] - mu) * rinv + bv[j];
                    v[j] = t > 0.f ? t : __expf(t) - 1.f;
                }
            } else {
                const float* A = (const float*)Av;
                if (gm < M) {
                    float4 a0 = *(const float4*)(A + (size_t)gm * 128 + k0);
                    float4 a1 = *(const float4*)(A + (size_t)gm * 128 + k0 + 4);
                    v[0] = a0.x; v[1] = a0.y; v[2] = a0.z; v[3] = a0.w;
                    v[4] = a1.x; v[5] = a1.y; v[6] = a1.z; v[7] = a1.w;
                } else {
#pragma unroll
                    for (int j = 0; j < 8; j++) v[j] = 0.f;
                }
            }
            short8 pk;
#pragma unroll
            for (int j = 0; j < 8; j++) pk[j] = (short)f2bf(v[j]);
            *(short8*)&As[row * 128 + (k0 ^ ((row & 7) << 3))] = pk;
        }
    }
    __syncthreads();

    const int lane = tid & 63;
    const int wid = tid >> 6;
    const int lr = lane & 15;
    const int lk = lane >> 4;

    short8 a[4][4];
#pragma unroll
    for (int rf = 0; rf < 4; rf++) {
        int row = rf * 16 + lr;
#pragma unroll
        for (int kc = 0; kc < 4; kc++) {
            int k0 = kc * 32 + lk * 8;
            a[rf][kc] = *(short8*)&As[row * 128 + (k0 ^ ((row & 7) << 3))];
        }
    }

    constexpr int NCF = BN / 64;
    const int nbase = wid * (BN / 4);

    const unsigned short* Bts[3] = {Bt0, Bt1, Bt2};
#pragma unroll
    for (int j = 0; j < 3; j++) {
        const unsigned short* Bt = Bts[j];
        short8 b[NCF][4];
#pragma unroll
        for (int cf = 0; cf < NCF; cf++) {
            int n = nbase + cf * 16 + lr;
#pragma unroll
            for (int kc = 0; kc < 4; kc++)
                b[cf][kc] = *(const short8*)(Bt + (size_t)n * 128 + kc * 32 + lk * 8);
        }
        f32x4 acc[4][NCF];
#pragma unroll
        for (int rf = 0; rf < 4; rf++)
#pragma unroll
            for (int cf = 0; cf < NCF; cf++) acc[rf][cf] = (f32x4){0.f, 0.f, 0.f, 0.f};
#pragma unroll
        for (int kc = 0; kc < 4; kc++)
#pragma unroll
            for (int rf = 0; rf < 4; rf++)
#pragma unroll
                for (int cf = 0; cf < NCF; cf++)
                    acc[rf][cf] = __builtin_amdgcn_mfma_f32_16x16x32_bf16(
                        a[rf][kc], b[cf][kc], acc[rf][cf], 0, 0, 0);
        if (j < 2) {
            unsigned short* C = (j == 0) ? C0 : C1;
#pragma unroll
            for (int rf = 0; rf < 4; rf++)
#pragma unroll
                for (int cf = 0; cf < NCF; cf++) {
                    int col = nbase + cf * 16 + lr;
#pragma unroll
                    for (int r = 0; r < 4; r++) {
                        int row = m0 + rf * 16 + lk * 4 + r;
                        if (row < M) C[(size_t)row * BN + col] = f2bf(acc[rf][cf][r]);
                    }
                }
        } else {
#pragma unroll
            for (int rf = 0; rf < 4; rf++)
#pragma unroll
                for (int cf = 0; cf < NCF; cf++) {
                    int col = nbase + cf * 16 + lr;
                    float bb = bias2[col];
#pragma unroll
                    for (int r = 0; r < 4; r++) {
                        int row = m0 + rf * 16 + lk * 4 + r;
                        if (row < M) {
                            if constexpr (OUTBF)
                                C2b[(size_t)row * BN + col] = f2bf(acc[rf][cf][r] + bb);
                            else
                                C2f[(size_t)row * BN + col] = acc[rf][cf][r] + bb;
                        }
                    }
                }
        }
    }
}

// ---------------- CSR build (by dst); self-loops placed at rowptr[d]; u16 entries ----------------
__global__ __launch_bounds__(256) void csr_count(const int* __restrict__ ei, int* __restrict__ deg) {
    int i = blockIdx.x * blockDim.x + threadIdx.x;
    int stride = gridDim.x * blockDim.x;
    for (int e = i; e < NE0; e += stride) atomicAdd(&deg[ei[NE0 + e]], 1);
}

__global__ __launch_bounds__(256) void scan1(const int* __restrict__ deg,
                                             int* __restrict__ locexc,
                                             int* __restrict__ blocksum) {
    __shared__ int s[256];
    const int t = threadIdx.x;
    const int g = blockIdx.x * 256 + t;
    int v = (g < NND) ? deg[g] + 1 : 0;   // +1: implicit self-loop
    s[t] = v;
    __syncthreads();
    for (int off = 1; off < 256; off <<= 1) {
        int x = (t >= off) ? s[t - off] : 0;
        __syncthreads();
        s[t] += x;
        __syncthreads();
    }
    if (g < NND) locexc[g] = s[t] - v;
    if (t == 255) blocksum[blockIdx.x] = s[255];
}

__global__ __launch_bounds__(256) void scan2(const int* __restrict__ blocksum,
                                             int* __restrict__ blockoff,
                                             int* __restrict__ rowptr) {
    __shared__ int s[256];
    const int t = threadIdx.x;
    int v = (t < SCAN_B) ? blocksum[t] : 0;
    s[t] = v;
    __syncthreads();
    for (int off = 1; off < 256; off <<= 1) {
        int x = (t >= off) ? s[t - off] : 0;
        __syncthreads();
        s[t] += x;
        __syncthreads();
    }
    if (t < SCAN_B) blockoff[t] = s[t] - v;
    if (t == 255) rowptr[NND] = s[255];
}

__global__ __launch_bounds__(256) void scan3(const int* __restrict__ locexc,
                                             const int* __restrict__ blockoff,
                                             int* __restrict__ rowptr,
                                             unsigned short* __restrict__ csrs) {
    const int g = blockIdx.x * 256 + threadIdx.x;
    if (g < NND) {
        int rp = locexc[g] + blockoff[g >> 8];
        rowptr[g] = rp;
        csrs[rp] = (unsigned short)g;   // self-loop first in each segment (src < 65536)
    }
}

__global__ __launch_bounds__(256) void csr_fill(const int* __restrict__ ei,
                                                const int* __restrict__ rowptr,
                                                int* __restrict__ cursor,
                                                unsigned short* __restrict__ csrs) {
    int i = blockIdx.x * blockDim.x + threadIdx.x;
    int stride = gridDim.x * blockDim.x;
    for (int e = i; e < NE0; e += stride) {
        int s = ei[e], d = ei[NE0 + e];
        int pos = atomicAdd(&cursor[d], 1);
        csrs[rowptr[d] + 1 + pos] = (unsigned short)s;   // +1: slot 0 is the self-loop
    }
}

// ---- fused logits + softmax aggregation, layer 1 (8 heads x 16) ----
__global__ __launch_bounds__(256) void aggr_l1(const int* __restrict__ rowptr,
                                               const unsigned short* __restrict__ csrs,
                                               const unsigned short* __restrict__ xl,
                                               const unsigned short* __restrict__ xr,
                                               const float* __restrict__ att,
                                               const float* __restrict__ b1,
                                               unsigned short* __restrict__ h,
                                               float2* __restrict__ partial) {
    const int lane = threadIdx.x & 63;
    const int wv = threadIdx.x >> 6;
    int wid = (blockIdx.x * blockDim.x + threadIdx.x) >> 6;
    const int nw = (gridDim.x * blockDim.x) >> 6;
    const int c = lane * 2;
    float2 attv = *(const float2*)(att + c);
    float2 b1v = *(const float2*)(b1 + c);
    float ts = 0.f, ts2 = 0.f;
    for (int d = wid; d < NND; d += nw) {
        int p0 = rowptr[d], p1 = rowptr[d + 1];
        float2 xrv = bf2x2(*(const unsigned int*)(xr + (size_t)d * 128 + c));
        float den0 = 0.f, den1 = 0.f, den2 = 0.f, den3 = 0.f;
        float a00 = 0.f, a01 = 0.f, a10 = 0.f, a11 = 0.f;
        float a20 = 0.f, a21 = 0.f, a30 = 0.f, a31 = 0.f;
        int i = p0;
        for (; i + 4 <= p1; i += 4) {
            int s0 = csrs[i], s1 = csrs[i + 1], s2 = csrs[i + 2], s3 = csrs[i + 3];
            float2 x0 = bf2x2(*(const unsigned int*)(xl + (size_t)s0 * 128 + c));
            float2 x1 = bf2x2(*(const unsigned int*)(xl + (size_t)s1 * 128 + c));
            float2 x2 = bf2x2(*(const unsigned int*)(xl + (size_t)s2 * 128 + c));
            float2 x3 = bf2x2(*(const unsigned int*)(xl + (size_t)s3 * 128 + c));
            float q0 = lrelu(x0.x + xrv.x) * attv.x + lrelu(x0.y + xrv.y) * attv.y;
            float q1 = lrelu(x1.x + xrv.x) * attv.x + lrelu(x1.y + xrv.y) * attv.y;
            float q2 = lrelu(x2.x + xrv.x) * attv.x + lrelu(x2.y + xrv.y) * attv.y;
            float q3 = lrelu(x3.x + xrv.x) * attv.x + lrelu(x3.y + xrv.y) * attv.y;
            q0 = dpp_add<0xB1>(q0); q0 = dpp_add<0x4E>(q0); q0 = dpp_add<0x141>(q0);
            q1 = dpp_add<0xB1>(q1); q1 = dpp_add<0x4E>(q1); q1 = dpp_add<0x141>(q1);
            q2 = dpp_add<0xB1>(q2); q2 = dpp_add<0x4E>(q2); q2 = dpp_add<0x141>(q2);
            q3 = dpp_add<0xB1>(q3); q3 = dpp_add<0x4E>(q3); q3 = dpp_add<0x141>(q3);
            float p0v = __expf(q0), p1v = __expf(q1), p2v = __expf(q2), p3v = __expf(q3);
            den0 += p0v; a00 = fmaf(p0v, x0.x, a00); a01 = fmaf(p0v, x0.y, a01);
            den1 += p1v; a10 = fmaf(p1v, x1.x, a10); a11 = fmaf(p1v, x1.y, a11);
            den2 += p2v; a20 = fmaf(p2v, x2.x, a20); a21 = fmaf(p2v, x2.y, a21);
            den3 += p3v; a30 = fmaf(p3v, x3.x, a30); a31 = fmaf(p3v, x3.y, a31);
        }
        for (; i < p1; i++) {
            int s0 = csrs[i];
            float2 x0 = bf2x2(*(const unsigned int*)(xl + (size_t)s0 * 128 + c));
            float q0 = lrelu(x0.x + xrv.x) * attv.x + lrelu(x0.y + xrv.y) * attv.y;
            q0 = dpp_add<0xB1>(q0); q0 = dpp_add<0x4E>(q0); q0 = dpp_add<0x141>(q0);
            float p0v = __expf(q0);
            den0 += p0v; a00 = fmaf(p0v, x0.x, a00); a01 = fmaf(p0v, x0.y, a01);
        }
        float den = (den0 + den1) + (den2 + den3);
        float a0 = (a00 + a10) + (a20 + a30);
        float a1 = (a01 + a11) + (a21 + a31);
        float inv = 1.f / den;
        unsigned int* hp = (unsigned int*)(h + (size_t)d * 128 + c);
        float2 hv = bf2x2(*hp);
        hv.x += a0 * inv + b1v.x;
        hv.y += a1 * inv + b1v.y;
        *hp = packbf(hv.x, hv.y);
        ts += hv.x + hv.y;
        ts2 += hv.x * hv.x + hv.y * hv.y;
    }
    __shared__ float red[8];
#pragma unroll
    for (int off = 32; off; off >>= 1) {
        ts += __shfl_down(ts, off);
        ts2 += __shfl_down(ts2, off);
    }
    if (lane == 0) { red[wv * 2] = ts; red[wv * 2 + 1] = ts2; }
    __syncthreads();
    if (threadIdx.x == 0) {
        float s = red[0] + red[2] + red[4] + red[6];
        float s2 = red[1] + red[3] + red[5] + red[7];
        partial[blockIdx.x] = make_float2(s, s2);
    }
}

__global__ __launch_bounds__(256) void ln_final2(const float2* __restrict__ part, int np,
                                                 float* __restrict__ musig) {
    double s = 0.0, s2 = 0.0;
    for (int i = threadIdx.x; i < np; i += 256) {
        float2 p = part[i];
        s += p.x;
        s2 += p.y;
    }
#pragma unroll
    for (int off = 32; off; off >>= 1) {
        s += __shfl_down(s, off);
        s2 += __shfl_down(s2, off);
    }
    __shared__ double red[8];
    const int wv = threadIdx.x >> 6;
    if ((threadIdx.x & 63) == 0) { red[wv * 2] = s; red[wv * 2 + 1] = s2; }
    __syncthreads();
    if (threadIdx.x == 0) {
        double S = red[0] + red[2] + red[4] + red[6];
        double S2 = red[1] + red[3] + red[5] + red[7];
        double inv_n = 1.0 / ((double)NND * 128.0);
        double mu = S * inv_n;
        double var = S2 * inv_n - mu * mu;
        musig[0] = (float)mu;
        musig[1] = (float)(1.0 / sqrt(var + 1e-5));
    }
}

// ---- fused logits + aggregation, layer 2 (1 head x 64) ----
__global__ __launch_bounds__(256) void aggr_l2(const int* __restrict__ rowptr,
                                               const unsigned short* __restrict__ csrs,
                                               const unsigned short* __restrict__ xl,
                                               const unsigned short* __restrict__ xr,
                                               const float* __restrict__ att,
                                               const float* __restrict__ b2,
                                               float* __restrict__ out) {
    const int hl = threadIdx.x & 31;
    int hwid = (blockIdx.x * blockDim.x + threadIdx.x) >> 5;
    const int nhw = (gridDim.x * blockDim.x) >> 5;
    const int c = hl * 2;
    float2 attv = *(const float2*)(att + c);
    float2 b2v = *(const float2*)(b2 + c);
    for (int d = hwid; d < NND; d += nhw) {
        int p0 = rowptr[d], p1 = rowptr[d + 1];
        float2 xrv = bf2x2(*(const unsigned int*)(xr + (size_t)d * 64 + c));
        float den0 = 0.f, den1 = 0.f, den2 = 0.f, den3 = 0.f;
        float a00 = 0.f, a01 = 0.f, a10 = 0.f, a11 = 0.f;
        float a20 = 0.f, a21 = 0.f, a30 = 0.f, a31 = 0.f;
        int i = p0;
        for (; i + 4 <= p1; i += 4) {
            int s0 = csrs[i], s1 = csrs[i + 1], s2 = csrs[i + 2], s3 = csrs[i + 3];
            float2 x0 = bf2x2(*(const unsigned int*)(xl + (size_t)s0 * 64 + c));
            float2 x1 = bf2x2(*(const unsigned int*)(xl + (size_t)s1 * 64 + c));
            float2 x2 = bf2x2(*(const unsigned int*)(xl + (size_t)s2 * 64 + c));
            float2 x3 = bf2x2(*(const unsigned int*)(xl + (size_t)s3 * 64 + c));
            float q0 = lrelu(x0.x + xrv.x) * attv.x + lrelu(x0.y + xrv.y) * attv.y;
            float q1 = lrelu(x1.x + xrv.x) * attv.x + lrelu(x1.y + xrv.y) * attv.y;
            float q2 = lrelu(x2.x + xrv.x) * attv.x + lrelu(x2.y + xrv.y) * attv.y;
            float q3 = lrelu(x3.x + xrv.x) * attv.x + lrelu(x3.y + xrv.y) * attv.y;
            q0 = dpp_add<0xB1>(q0); q0 = dpp_add<0x4E>(q0); q0 = dpp_add<0x141>(q0);
            q0 = dpp_add<0x140>(q0); q0 += __shfl_xor(q0, 16);
            q1 = dpp_add<0xB1>(q1); q1 = dpp_add<0x4E>(q1); q1 = dpp_add<0x141>(q1);
            q1 = dpp_add<0x140>(q1); q1 += __shfl_xor(q1, 16);
            q2 = dpp_add<0xB1>(q2); q2 = dpp_add<0x4E>(q2); q2 = dpp_add<0x141>(q2);
            q2 = dpp_add<0x140>(q2); q2 += __shfl_xor(q2, 16);
            q3 = dpp_add<0xB1>(q3); q3 = dpp_add<0x4E>(q3); q3 = dpp_add<0x141>(q3);
            q3 = dpp_add<0x140>(q3); q3 += __shfl_xor(q3, 16);
            float p0v = __expf(q0), p1v = __expf(q1), p2v = __expf(q2), p3v = __expf(q3);
            den0 += p0v; a00 = fmaf(p0v, x0.x, a00); a01 = fmaf(p0v, x0.y, a01);
            den1 += p1v; a10 = fmaf(p1v, x1.x, a10); a11 = fmaf(p1v, x1.y, a11);
            den2 += p2v; a20 = fmaf(p2v, x2.x, a20); a21 = fmaf(p2v, x2.y, a21);
            den3 += p3v; a30 = fmaf(p3v, x3.x, a30); a31 = fmaf(p3v, x3.y, a31);
        }
        for (; i < p1; i++) {
            int s0 = csrs[i];
            float2 x0 = bf2x2(*(const unsigned int*)(xl + (size_t)s0 * 64 + c));
            float q0 = lrelu(x0.x + xrv.x) * attv.x + lrelu(x0.y + xrv.y) * attv.y;
            q0 = dpp_add<0xB1>(q0); q0 = dpp_add<0x4E>(q0); q0 = dpp_add<0x141>(q0);
            q0 = dpp_add<0x140>(q0); q0 += __shfl_xor(q0, 16);
            float p0v = __expf(q0);
            den0 += p0v; a00 = fmaf(p0v, x0.x, a00); a01 = fmaf(p0v, x0.y, a01);
        }
        float den = (den0 + den1) + (den2 + den3);
        float a0 = (a00 + a10) + (a20 + a30);
        float a1 = (a01 + a11) + (a21 + a31);
        float inv = 1.f / den;
        float2 ov = *(float2*)(out + (size_t)d * 64 + c);
        ov.x += a0 * inv + b2v.x;
        ov.y += a1 * inv + b2v.y;
        *(float2*)(out + (size_t)d * 64 + c) = ov;
    }
}

extern "C" void kernel_launch(void* const* d_in, const int* in_sizes, int n_in,
                              void* d_out, int out_size, void* d_ws, size_t ws_size,
                              hipStream_t stream) {
    (void)in_sizes; (void)n_in; (void)out_size; (void)ws_size;
    const float* x    = (const float*)d_in[0];
    const int*   ei   = (const int*)d_in[1];
    const float* W1l  = (const float*)d_in[2];
    const float* W1r  = (const float*)d_in[3];
    const float* att1 = (const float*)d_in[4];
    const float* b1   = (const float*)d_in[5];
    const float* s1W  = (const float*)d_in[6];
    const float* s1b  = (const float*)d_in[7];
    const float* lnw  = (const float*)d_in[8];
    const float* lnb  = (const float*)d_in[9];
    const float* W2l  = (const float*)d_in[10];
    const float* W2r  = (const float*)d_in[11];
    const float* att2 = (const float*)d_in[12];
    const float* b2   = (const float*)d_in[13];
    const float* s2W  = (const float*)d_in[14];
    const float* s2b  = (const float*)d_in[15];
    float* out = (float*)d_out;

    char* ws = (char*)d_ws;
    size_t off = 0;
    auto alloc = [&](size_t bytes) {
        size_t o = off;
        off = (off + bytes + 255) & ~(size_t)255;
        return o;
    };
    unsigned short* xl = (unsigned short*)(ws + alloc((size_t)NND * 128 * 2));  // layer2 reuses (N x 64)
    unsigned short* xr = (unsigned short*)(ws + alloc((size_t)NND * 128 * 2));
    unsigned short* h  = (unsigned short*)(ws + alloc((size_t)NND * 128 * 2));  // bf16
    int* deg     = (int*)(ws + alloc((size_t)NND * 4));
    int* rowptr  = (int*)(ws + alloc((size_t)(NND + 1) * 4));
    int* cursor  = (int*)(ws + alloc((size_t)NND * 4));
    unsigned short* csrs = (unsigned short*)(ws + alloc((size_t)NET * 2));  // u16 src ids
    int* locexc  = (int*)(ws + alloc((size_t)NND * 4));
    int* blocksum= (int*)(ws + alloc((size_t)SCAN_B * 4));
    int* blockoff= (int*)(ws + alloc((size_t)SCAN_B * 4));
    unsigned short* Bt1 = (unsigned short*)(ws + alloc((size_t)3 * 128 * 128 * 2));
    unsigned short* Bt2 = (unsigned short*)(ws + alloc((size_t)3 * 64 * 128 * 2));
    float2* partial = (float2*)(ws + alloc((size_t)12500 * 8));
    float* musig = (float*)(ws + alloc(8));

    hipMemsetAsync(deg, 0, (size_t)NND * 4, stream);
    hipMemsetAsync(cursor, 0, (size_t)NND * 4, stream);

    // CSR by dst (shared by both layers); self-loop occupies slot 0 of each segment
    csr_count<<<1024, 256, 0, stream>>>(ei, deg);
    scan1<<<SCAN_B, 256, 0, stream>>>(deg, locexc, blocksum);
    scan2<<<1, 256, 0, stream>>>(blocksum, blockoff, rowptr);
    scan3<<<SCAN_B, 256, 0, stream>>>(locexc, blockoff, rowptr, csrs);
    csr_fill<<<1024, 256, 0, stream>>>(ei, rowptr, cursor, csrs);

    // weight transpose + bf16 (both layers, one launch)
    wt_prep_all<<<288, 256, 0, stream>>>(W1l, W1r, s1W, W2l, W2r, s2W, Bt1, Bt2);

    // Layer 1: xl=x@W1l, xr=x@W1r (bf16), h=x@s1W+s1b (bf16)
    gemm3_mfma<128, false, true><<<782, 256, 0, stream>>>(
        (const void*)x, Bt1, Bt1 + 16384, Bt1 + 32768, s1b,
        xl, xr, h, nullptr, nullptr, nullptr, nullptr, NND);
    aggr_l1<<<12500, 256, 0, stream>>>(rowptr, csrs, xl, xr, att1, b1, h, partial);
    ln_final2<<<1, 256, 0, stream>>>(partial, 12500, musig);

    // Layer 2: xl2=hln@W2l, xr2=hln@W2r (bf16), out=hln@s2W+s2b (f32)
    gemm3_mfma<64, true, false><<<782, 256, 0, stream>>>(
        (const void*)h, Bt2, Bt2 + 8192, Bt2 + 16384, s2b,
        xl, xr, nullptr, out, musig, lnw, lnb, NND);
    aggr_l2<<<6250, 256, 0, stream>>>(rowptr, csrs, xl, xr, att2, b2, out);
}

// Round 11
// 246.749 us; speedup vs baseline: 2.4137x; 1.0091x over previous
//
#include <hip/hip_runtime.h>
#include <math.h>

#define NND 50000      // nodes
#define NE0 800000     // raw edges
#define NET 850000     // edges + self loops
#define SCAN_B 196     // ceil(NND/256)
#define NPART 8        // dst partitions (== XCD count)
#define DPP_RANGE 6250 // NND / NPART

using short8  = __attribute__((ext_vector_type(8))) short;
using ushort8 = __attribute__((ext_vector_type(8))) unsigned short;
using f32x4   = __attribute__((ext_vector_type(4))) float;

__device__ __forceinline__ float lrelu(float v) { return fmaxf(v, 0.2f * v); }

__device__ __forceinline__ unsigned short f2bf(float f) {
    unsigned int u = __float_as_uint(f);
    u = (u + 0x7fff + ((u >> 16) & 1)) >> 16;   // RNE
    return (unsigned short)u;
}
__device__ __forceinline__ float2 bf2x2(unsigned int u) {
    float2 r;
    r.x = __uint_as_float(u << 16);
    r.y = __uint_as_float(u & 0xffff0000u);
    return r;
}
__device__ __forceinline__ unsigned int packbf(float x, float y) {
    return (unsigned int)f2bf(x) | ((unsigned int)f2bf(y) << 16);
}

// butterfly-add via DPP (VALU pipe): 0xB1 xor1 | 0x4E xor2 | 0x141 xor4-when-
// uniform-in-4 | 0x140 xor8-when-uniform-in-8
template <int CTRL>
__device__ __forceinline__ float dpp_add(float v) {
    int j = __builtin_amdgcn_update_dpp(0, __float_as_int(v), CTRL, 0xf, 0xf, true);
    return v + __int_as_float(j);
}

// ---- weight prep, both layers in one launch: [128][N] f32 -> [N][128] bf16 ----
__global__ __launch_bounds__(256) void wt_prep_all(
    const float* __restrict__ A0, const float* __restrict__ A1, const float* __restrict__ A2,
    const float* __restrict__ B0, const float* __restrict__ B1, const float* __restrict__ B2,
    unsigned short* __restrict__ T1, unsigned short* __restrict__ T2) {
    const int L1 = 3 * 128 * 128;            // 49152
    const int L2 = 3 * 64 * 128;             // 24576
    int idx = blockIdx.x * blockDim.x + threadIdx.x;
    if (idx < L1) {
        int which = idx / 16384, rem = idx - which * 16384;
        int k = rem >> 7, n = rem & 127;
        const float* S = which == 0 ? A0 : (which == 1 ? A1 : A2);
        T1[which * 16384 + n * 128 + k] = f2bf(S[rem]);
    } else if (idx < L1 + L2) {
        int idx2 = idx - L1;
        int which = idx2 / 8192, rem = idx2 - which * 8192;
        int k = rem >> 6, n = rem & 63;
        const float* S = which == 0 ? B0 : (which == 1 ? B1 : B2);
        T2[which * 8192 + n * 128 + k] = f2bf(S[rem]);
    }
}

// ---- MFMA GEMM trio: C0=A@B0 (bf16), C1=A@B1 (bf16), C2=A@B2+bias2 ----
template <int BN, bool LN, bool OUTBF>
__global__ __launch_bounds__(256) void gemm3_mfma(
    const void* __restrict__ Av,
    const unsigned short* __restrict__ Bt0, const unsigned short* __restrict__ Bt1,
    const unsigned short* __restrict__ Bt2, const float* __restrict__ bias2,
    unsigned short* __restrict__ C0, unsigned short* __restrict__ C1,
    unsigned short* __restrict__ C2b, float* __restrict__ C2f,
    const float* __restrict__ musig, const float* __restrict__ lnw,
    const float* __restrict__ lnb, int M) {
    __shared__ __align__(16) unsigned short As[64 * 128];   // bf16, XOR-swizzled
    const int tid = threadIdx.x;
    const int m0 = blockIdx.x * 64;

    float mu = 0.f, rinv = 1.f;
    if constexpr (LN) { mu = musig[0]; rinv = musig[1]; }

    {
        const int row = tid >> 2, qc = tid & 3;
        const int gm = m0 + row;
#pragma unroll
        for (int i = 0; i < 4; i++) {
            int k0 = qc * 32 + i * 8;
            float v[8];
            if constexpr (LN) {
                const unsigned short* A = (const unsigned short*)Av;
                if (gm < M) {
                    ushort8 us = *(const ushort8*)(A + (size_t)gm * 128 + k0);
#pragma unroll
                    for (int j = 0; j < 8; j++) v[j] = __uint_as_float((unsigned int)us[j] << 16);
                } else {
#pragma unroll
                    for (int j = 0; j < 8; j++) v[j] = 0.f;
                }
                float4 w0 = *(const float4*)(lnw + k0);
                float4 w1 = *(const float4*)(lnw + k0 + 4);
                float4 b0 = *(const float4*)(lnb + k0);
                float4 b1 = *(const float4*)(lnb + k0 + 4);
                float wv[8] = {w0.x, w0.y, w0.z, w0.w, w1.x, w1.y, w1.z, w1.w};
                float bv[8] = {b0.x, b0.y, b0.z, b0.w, b1.x, b1.y, b1.z, b1.w};
#pragma unroll
                for (int j = 0; j < 8; j++) {
                    float t = wv[j] * (v[j] - mu) * rinv + bv[j];
                    v[j] = t > 0.f ? t : __expf(t) - 1.f;
                }
            } else {
                const float* A = (const float*)Av;
                if (gm < M) {
                    float4 a0 = *(const float4*)(A + (size_t)gm * 128 + k0);
                    float4 a1 = *(const float4*)(A + (size_t)gm * 128 + k0 + 4);
                    v[0] = a0.x; v[1] = a0.y; v[2] = a0.z; v[3] = a0.w;
                    v[4] = a1.x; v[5] = a1.y; v[6] = a1.z; v[7] = a1.w;
                } else {
#pragma unroll
                    for (int j = 0; j < 8; j++) v[j] = 0.f;
                }
            }
            short8 pk;
#pragma unroll
            for (int j = 0; j < 8; j++) pk[j] = (short)f2bf(v[j]);
            *(short8*)&As[row * 128 + (k0 ^ ((row & 7) << 3))] = pk;
        }
    }
    __syncthreads();

    const int lane = tid & 63;
    const int wid = tid >> 6;
    const int lr = lane & 15;
    const int lk = lane >> 4;

    short8 a[4][4];
#pragma unroll
    for (int rf = 0; rf < 4; rf++) {
        int row = rf * 16 + lr;
#pragma unroll
        for (int kc = 0; kc < 4; kc++) {
            int k0 = kc * 32 + lk * 8;
            a[rf][kc] = *(short8*)&As[row * 128 + (k0 ^ ((row & 7) << 3))];
        }
    }

    constexpr int NCF = BN / 64;
    const int nbase = wid * (BN / 4);

    const unsigned short* Bts[3] = {Bt0, Bt1, Bt2};
#pragma unroll
    for (int j = 0; j < 3; j++) {
        const unsigned short* Bt = Bts[j];
        short8 b[NCF][4];
#pragma unroll
        for (int cf = 0; cf < NCF; cf++) {
            int n = nbase + cf * 16 + lr;
#pragma unroll
            for (int kc = 0; kc < 4; kc++)
                b[cf][kc] = *(const short8*)(Bt + (size_t)n * 128 + kc * 32 + lk * 8);
        }
        f32x4 acc[4][NCF];
#pragma unroll
        for (int rf = 0; rf < 4; rf++)
#pragma unroll
            for (int cf = 0; cf < NCF; cf++) acc[rf][cf] = (f32x4){0.f, 0.f, 0.f, 0.f};
#pragma unroll
        for (int kc = 0; kc < 4; kc++)
#pragma unroll
            for (int rf = 0; rf < 4; rf++)
#pragma unroll
                for (int cf = 0; cf < NCF; cf++)
                    acc[rf][cf] = __builtin_amdgcn_mfma_f32_16x16x32_bf16(
                        a[rf][kc], b[cf][kc], acc[rf][cf], 0, 0, 0);
        if (j < 2) {
            unsigned short* C = (j == 0) ? C0 : C1;
#pragma unroll
            for (int rf = 0; rf < 4; rf++)
#pragma unroll
                for (int cf = 0; cf < NCF; cf++) {
                    int col = nbase + cf * 16 + lr;
#pragma unroll
                    for (int r = 0; r < 4; r++) {
                        int row = m0 + rf * 16 + lk * 4 + r;
                        if (row < M) C[(size_t)row * BN + col] = f2bf(acc[rf][cf][r]);
                    }
                }
        } else {
#pragma unroll
            for (int rf = 0; rf < 4; rf++)
#pragma unroll
                for (int cf = 0; cf < NCF; cf++) {
                    int col = nbase + cf * 16 + lr;
                    float bb = bias2[col];
#pragma unroll
                    for (int r = 0; r < 4; r++) {
                        int row = m0 + rf * 16 + lk * 4 + r;
                        if (row < M) {
                            if constexpr (OUTBF)
                                C2b[(size_t)row * BN + col] = f2bf(acc[rf][cf][r] + bb);
                            else
                                C2f[(size_t)row * BN + col] = acc[rf][cf][r] + bb;
                        }
                    }
                }
        }
    }
}

// ---------------- CSR build (by dst); self-loops placed at rowptr[d]; u16 entries ----------------
__global__ __launch_bounds__(256) void csr_count(const int* __restrict__ ei, int* __restrict__ deg) {
    int i = blockIdx.x * blockDim.x + threadIdx.x;
    int stride = gridDim.x * blockDim.x;
    for (int e = i; e < NE0; e += stride) atomicAdd(&deg[ei[NE0 + e]], 1);
}

__global__ __launch_bounds__(256) void scan1(const int* __restrict__ deg,
                                             int* __restrict__ locexc,
                                             int* __restrict__ blocksum) {
    __shared__ int s[256];
    const int t = threadIdx.x;
    const int g = blockIdx.x * 256 + t;
    int v = (g < NND) ? deg[g] + 1 : 0;   // +1: implicit self-loop
    s[t] = v;
    __syncthreads();
    for (int off = 1; off < 256; off <<= 1) {
        int x = (t >= off) ? s[t - off] : 0;
        __syncthreads();
        s[t] += x;
        __syncthreads();
    }
    if (g < NND) locexc[g] = s[t] - v;
    if (t == 255) blocksum[blockIdx.x] = s[255];
}

__global__ __launch_bounds__(256) void scan2(const int* __restrict__ blocksum,
                                             int* __restrict__ blockoff,
                                             int* __restrict__ rowptr) {
    __shared__ int s[256];
    const int t = threadIdx.x;
    int v = (t < SCAN_B) ? blocksum[t] : 0;
    s[t] = v;
    __syncthreads();
    for (int off = 1; off < 256; off <<= 1) {
        int x = (t >= off) ? s[t - off] : 0;
        __syncthreads();
        s[t] += x;
        __syncthreads();
    }
    if (t < SCAN_B) blockoff[t] = s[t] - v;
    if (t == 255) rowptr[NND] = s[255];
}

__global__ __launch_bounds__(256) void scan3(const int* __restrict__ locexc,
                                             const int* __restrict__ blockoff,
                                             int* __restrict__ rowptr,
                                             unsigned short* __restrict__ csrs) {
    const int g = blockIdx.x * 256 + threadIdx.x;
    if (g < NND) {
        int rp = locexc[g] + blockoff[g >> 8];
        rowptr[g] = rp;
        csrs[rp] = (unsigned short)g;   // self-loop first in each segment (src < 65536)
    }
}

// partitioned fill: block handles only dsts in range (blockIdx&7); blocks with
// equal blockIdx&7 land on the same XCD (round-robin dispatch), so each XCD's
// csrs slice (~212KB) stays L2-resident and is written back once. Partition
// mismatch only costs extra reads, never correctness.
__global__ __launch_bounds__(256) void csr_fill(const int* __restrict__ ei,
                                                const int* __restrict__ rowptr,
                                                int* __restrict__ cursor,
                                                unsigned short* __restrict__ csrs) {
    const int part = blockIdx.x & (NPART - 1);
    const int dlo = part * DPP_RANGE, dhi = dlo + DPP_RANGE;
    const int nb = gridDim.x >> 3;
    const int bi = blockIdx.x >> 3;
    for (int e = bi * 256 + threadIdx.x; e < NE0; e += nb * 256) {
        int d = ei[NE0 + e];
        if (d >= dlo && d < dhi) {
            int s = ei[e];
            int pos = atomicAdd(&cursor[d], 1);
            csrs[rowptr[d] + 1 + pos] = (unsigned short)s;   // +1: slot 0 is self-loop
        }
    }
}

// ---- fused logits + softmax aggregation, layer 1 (8 heads x 16) ----
__global__ __launch_bounds__(256) void aggr_l1(const int* __restrict__ rowptr,
                                               const unsigned short* __restrict__ csrs,
                                               const unsigned short* __restrict__ xl,
                                               const unsigned short* __restrict__ xr,
                                               const float* __restrict__ att,
                                               const float* __restrict__ b1,
                                               unsigned short* __restrict__ h,
                                               float2* __restrict__ partial) {
    const int lane = threadIdx.x & 63;
    const int wv = threadIdx.x >> 6;
    int wid = (blockIdx.x * blockDim.x + threadIdx.x) >> 6;
    const int nw = (gridDim.x * blockDim.x) >> 6;
    const int c = lane * 2;
    float2 attv = *(const float2*)(att + c);
    float2 b1v = *(const float2*)(b1 + c);
    float ts = 0.f, ts2 = 0.f;
    for (int d = wid; d < NND; d += nw) {
        int p0 = rowptr[d], p1 = rowptr[d + 1];
        float2 xrv = bf2x2(*(const unsigned int*)(xr + (size_t)d * 128 + c));
        float den0 = 0.f, den1 = 0.f, den2 = 0.f, den3 = 0.f;
        float a00 = 0.f, a01 = 0.f, a10 = 0.f, a11 = 0.f;
        float a20 = 0.f, a21 = 0.f, a30 = 0.f, a31 = 0.f;
        int i = p0;
        for (; i + 4 <= p1; i += 4) {
            int s0 = csrs[i], s1 = csrs[i + 1], s2 = csrs[i + 2], s3 = csrs[i + 3];
            float2 x0 = bf2x2(*(const unsigned int*)(xl + (size_t)s0 * 128 + c));
            float2 x1 = bf2x2(*(const unsigned int*)(xl + (size_t)s1 * 128 + c));
            float2 x2 = bf2x2(*(const unsigned int*)(xl + (size_t)s2 * 128 + c));
            float2 x3 = bf2x2(*(const unsigned int*)(xl + (size_t)s3 * 128 + c));
            float q0 = lrelu(x0.x + xrv.x) * attv.x + lrelu(x0.y + xrv.y) * attv.y;
            float q1 = lrelu(x1.x + xrv.x) * attv.x + lrelu(x1.y + xrv.y) * attv.y;
            float q2 = lrelu(x2.x + xrv.x) * attv.x + lrelu(x2.y + xrv.y) * attv.y;
            float q3 = lrelu(x3.x + xrv.x) * attv.x + lrelu(x3.y + xrv.y) * attv.y;
            q0 = dpp_add<0xB1>(q0); q0 = dpp_add<0x4E>(q0); q0 = dpp_add<0x141>(q0);
            q1 = dpp_add<0xB1>(q1); q1 = dpp_add<0x4E>(q1); q1 = dpp_add<0x141>(q1);
            q2 = dpp_add<0xB1>(q2); q2 = dpp_add<0x4E>(q2); q2 = dpp_add<0x141>(q2);
            q3 = dpp_add<0xB1>(q3); q3 = dpp_add<0x4E>(q3); q3 = dpp_add<0x141>(q3);
            float p0v = __expf(q0), p1v = __expf(q1), p2v = __expf(q2), p3v = __expf(q3);
            den0 += p0v; a00 = fmaf(p0v, x0.x, a00); a01 = fmaf(p0v, x0.y, a01);
            den1 += p1v; a10 = fmaf(p1v, x1.x, a10); a11 = fmaf(p1v, x1.y, a11);
            den2 += p2v; a20 = fmaf(p2v, x2.x, a20); a21 = fmaf(p2v, x2.y, a21);
            den3 += p3v; a30 = fmaf(p3v, x3.x, a30); a31 = fmaf(p3v, x3.y, a31);
        }
        for (; i < p1; i++) {
            int s0 = csrs[i];
            float2 x0 = bf2x2(*(const unsigned int*)(xl + (size_t)s0 * 128 + c));
            float q0 = lrelu(x0.x + xrv.x) * attv.x + lrelu(x0.y + xrv.y) * attv.y;
            q0 = dpp_add<0xB1>(q0); q0 = dpp_add<0x4E>(q0); q0 = dpp_add<0x141>(q0);
            float p0v = __expf(q0);
            den0 += p0v; a00 = fmaf(p0v, x0.x, a00); a01 = fmaf(p0v, x0.y, a01);
        }
        float den = (den0 + den1) + (den2 + den3);
        float a0 = (a00 + a10) + (a20 + a30);
        float a1 = (a01 + a11) + (a21 + a31);
        float inv = 1.f / den;
        unsigned int* hp = (unsigned int*)(h + (size_t)d * 128 + c);
        float2 hv = bf2x2(*hp);
        hv.x += a0 * inv + b1v.x;
        hv.y += a1 * inv + b1v.y;
        *hp = packbf(hv.x, hv.y);
        ts += hv.x + hv.y;
        ts2 += hv.x * hv.x + hv.y * hv.y;
    }
    __shared__ float red[8];
#pragma unroll
    for (int off = 32; off; off >>= 1) {
        ts += __shfl_down(ts, off);
        ts2 += __shfl_down(ts2, off);
    }
    if (lane == 0) { red[wv * 2] = ts; red[wv * 2 + 1] = ts2; }
    __syncthreads();
    if (threadIdx.x == 0) {
        float s = red[0] + red[2] + red[4] + red[6];
        float s2 = red[1] + red[3] + red[5] + red[7];
        partial[blockIdx.x] = make_float2(s, s2);
    }
}

__global__ __launch_bounds__(256) void ln_final2(const float2* __restrict__ part, int np,
                                                 float* __restrict__ musig) {
    double s = 0.0, s2 = 0.0;
    for (int i = threadIdx.x; i < np; i += 256) {
        float2 p = part[i];
        s += p.x;
        s2 += p.y;
    }
#pragma unroll
    for (int off = 32; off; off >>= 1) {
        s += __shfl_down(s, off);
        s2 += __shfl_down(s2, off);
    }
    __shared__ double red[8];
    const int wv = threadIdx.x >> 6;
    if ((threadIdx.x & 63) == 0) { red[wv * 2] = s; red[wv * 2 + 1] = s2; }
    __syncthreads();
    if (threadIdx.x == 0) {
        double S = red[0] + red[2] + red[4] + red[6];
        double S2 = red[1] + red[3] + red[5] + red[7];
        double inv_n = 1.0 / ((double)NND * 128.0);
        double mu = S * inv_n;
        double var = S2 * inv_n - mu * mu;
        musig[0] = (float)mu;
        musig[1] = (float)(1.0 / sqrt(var + 1e-5));
    }
}

// ---- fused logits + aggregation, layer 2 (1 head x 64) ----
__global__ __launch_bounds__(256) void aggr_l2(const int* __restrict__ rowptr,
                                               const unsigned short* __restrict__ csrs,
                                               const unsigned short* __restrict__ xl,
                                               const unsigned short* __restrict__ xr,
                                               const float* __restrict__ att,
                                               const float* __restrict__ b2,
                                               float* __restrict__ out) {
    const int hl = threadIdx.x & 31;
    int hwid = (blockIdx.x * blockDim.x + threadIdx.x) >> 5;
    const int nhw = (gridDim.x * blockDim.x) >> 5;
    const int c = hl * 2;
    float2 attv = *(const float2*)(att + c);
    float2 b2v = *(const float2*)(b2 + c);
    for (int d = hwid; d < NND; d += nhw) {
        int p0 = rowptr[d], p1 = rowptr[d + 1];
        float2 xrv = bf2x2(*(const unsigned int*)(xr + (size_t)d * 64 + c));
        float den0 = 0.f, den1 = 0.f, den2 = 0.f, den3 = 0.f;
        float a00 = 0.f, a01 = 0.f, a10 = 0.f, a11 = 0.f;
        float a20 = 0.f, a21 = 0.f, a30 = 0.f, a31 = 0.f;
        int i = p0;
        for (; i + 4 <= p1; i += 4) {
            int s0 = csrs[i], s1 = csrs[i + 1], s2 = csrs[i + 2], s3 = csrs[i + 3];
            float2 x0 = bf2x2(*(const unsigned int*)(xl + (size_t)s0 * 64 + c));
            float2 x1 = bf2x2(*(const unsigned int*)(xl + (size_t)s1 * 64 + c));
            float2 x2 = bf2x2(*(const unsigned int*)(xl + (size_t)s2 * 64 + c));
            float2 x3 = bf2x2(*(const unsigned int*)(xl + (size_t)s3 * 64 + c));
            float q0 = lrelu(x0.x + xrv.x) * attv.x + lrelu(x0.y + xrv.y) * attv.y;
            float q1 = lrelu(x1.x + xrv.x) * attv.x + lrelu(x1.y + xrv.y) * attv.y;
            float q2 = lrelu(x2.x + xrv.x) * attv.x + lrelu(x2.y + xrv.y) * attv.y;
            float q3 = lrelu(x3.x + xrv.x) * attv.x + lrelu(x3.y + xrv.y) * attv.y;
            q0 = dpp_add<0xB1>(q0); q0 = dpp_add<0x4E>(q0); q0 = dpp_add<0x141>(q0);
            q0 = dpp_add<0x140>(q0); q0 += __shfl_xor(q0, 16);
            q1 = dpp_add<0xB1>(q1); q1 = dpp_add<0x4E>(q1); q1 = dpp_add<0x141>(q1);
            q1 = dpp_add<0x140>(q1); q1 += __shfl_xor(q1, 16);
            q2 = dpp_add<0xB1>(q2); q2 = dpp_add<0x4E>(q2); q2 = dpp_add<0x141>(q2);
            q2 = dpp_add<0x140>(q2); q2 += __shfl_xor(q2, 16);
            q3 = dpp_add<0xB1>(q3); q3 = dpp_add<0x4E>(q3); q3 = dpp_add<0x141>(q3);
            q3 = dpp_add<0x140>(q3); q3 += __shfl_xor(q3, 16);
            float p0v = __expf(q0), p1v = __expf(q1), p2v = __expf(q2), p3v = __expf(q3);
            den0 += p0v; a00 = fmaf(p0v, x0.x, a00); a01 = fmaf(p0v, x0.y, a01);
            den1 += p1v; a10 = fmaf(p1v, x1.x, a10); a11 = fmaf(p1v, x1.y, a11);
            den2 += p2v; a20 = fmaf(p2v, x2.x, a20); a21 = fmaf(p2v, x2.y, a21);
            den3 += p3v; a30 = fmaf(p3v, x3.x, a30); a31 = fmaf(p3v, x3.y, a31);
        }
        for (; i < p1; i++) {
            int s0 = csrs[i];
            float2 x0 = bf2x2(*(const unsigned int*)(xl + (size_t)s0 * 64 + c));
            float q0 = lrelu(x0.x + xrv.x) * attv.x + lrelu(x0.y + xrv.y) * attv.y;
            q0 = dpp_add<0xB1>(q0); q0 = dpp_add<0x4E>(q0); q0 = dpp_add<0x141>(q0);
            q0 = dpp_add<0x140>(q0); q0 += __shfl_xor(q0, 16);
            float p0v = __expf(q0);
            den0 += p0v; a00 = fmaf(p0v, x0.x, a00); a01 = fmaf(p0v, x0.y, a01);
        }
        float den = (den0 + den1) + (den2 + den3);
        float a0 = (a00 + a10) + (a20 + a30);
        float a1 = (a01 + a11) + (a21 + a31);
        float inv = 1.f / den;
        float2 ov = *(float2*)(out + (size_t)d * 64 + c);
        ov.x += a0 * inv + b2v.x;
        ov.y += a1 * inv + b2v.y;
        *(float2*)(out + (size_t)d * 64 + c) = ov;
    }
}

extern "C" void kernel_launch(void* const* d_in, const int* in_sizes, int n_in,
                              void* d_out, int out_size, void* d_ws, size_t ws_size,
                              hipStream_t stream) {
    (void)in_sizes; (void)n_in; (void)out_size; (void)ws_size;
    const float* x    = (const float*)d_in[0];
    const int*   ei   = (const int*)d_in[1];
    const float* W1l  = (const float*)d_in[2];
    const float* W1r  = (const float*)d_in[3];
    const float* att1 = (const float*)d_in[4];
    const float* b1   = (const float*)d_in[5];
    const float* s1W  = (const float*)d_in[6];
    const float* s1b  = (const float*)d_in[7];
    const float* lnw  = (const float*)d_in[8];
    const float* lnb  = (const float*)d_in[9];
    const float* W2l  = (const float*)d_in[10];
    const float* W2r  = (const float*)d_in[11];
    const float* att2 = (const float*)d_in[12];
    const float* b2   = (const float*)d_in[13];
    const float* s2W  = (const float*)d_in[14];
    const float* s2b  = (const float*)d_in[15];
    float* out = (float*)d_out;

    char* ws = (char*)d_ws;
    size_t off = 0;
    auto alloc = [&](size_t bytes) {
        size_t o = off;
        off = (off + bytes + 255) & ~(size_t)255;
        return o;
    };
    unsigned short* xl = (unsigned short*)(ws + alloc((size_t)NND * 128 * 2));  // layer2 reuses (N x 64)
    unsigned short* xr = (unsigned short*)(ws + alloc((size_t)NND * 128 * 2));
    unsigned short* h  = (unsigned short*)(ws + alloc((size_t)NND * 128 * 2));  // bf16
    int* deg     = (int*)(ws + alloc((size_t)NND * 4));
    int* rowptr  = (int*)(ws + alloc((size_t)(NND + 1) * 4));
    int* cursor  = (int*)(ws + alloc((size_t)NND * 4));
    unsigned short* csrs = (unsigned short*)(ws + alloc((size_t)NET * 2));  // u16 src ids
    int* locexc  = (int*)(ws + alloc((size_t)NND * 4));
    int* blocksum= (int*)(ws + alloc((size_t)SCAN_B * 4));
    int* blockoff= (int*)(ws + alloc((size_t)SCAN_B * 4));
    unsigned short* Bt1 = (unsigned short*)(ws + alloc((size_t)3 * 128 * 128 * 2));
    unsigned short* Bt2 = (unsigned short*)(ws + alloc((size_t)3 * 64 * 128 * 2));
    float2* partial = (float2*)(ws + alloc((size_t)12500 * 8));
    float* musig = (float*)(ws + alloc(8));

    hipMemsetAsync(deg, 0, (size_t)NND * 4, stream);
    hipMemsetAsync(cursor, 0, (size_t)NND * 4, stream);

    // CSR by dst (shared by both layers); self-loop occupies slot 0 of each segment
    csr_count<<<1024, 256, 0, stream>>>(ei, deg);
    scan1<<<SCAN_B, 256, 0, stream>>>(deg, locexc, blocksum);
    scan2<<<1, 256, 0, stream>>>(blocksum, blockoff, rowptr);
    scan3<<<SCAN_B, 256, 0, stream>>>(locexc, blockoff, rowptr, csrs);
    csr_fill<<<2048, 256, 0, stream>>>(ei, rowptr, cursor, csrs);

    // weight transpose + bf16 (both layers, one launch)
    wt_prep_all<<<288, 256, 0, stream>>>(W1l, W1r, s1W, W2l, W2r, s2W, Bt1, Bt2);

    // Layer 1: xl=x@W1l, xr=x@W1r (bf16), h=x@s1W+s1b (bf16)
    gemm3_mfma<128, false, true><<<782, 256, 0, stream>>>(
        (const void*)x, Bt1, Bt1 + 16384, Bt1 + 32768, s1b,
        xl, xr, h, nullptr, nullptr, nullptr, nullptr, NND);
    aggr_l1<<<12500, 256, 0, stream>>>(rowptr, csrs, xl, xr, att1, b1, h, partial);
    ln_final2<<<1, 256, 0, stream>>>(partial, 12500, musig);

    // Layer 2: xl2=hln@W2l, xr2=hln@W2r (bf16), out=hln@s2W+s2b (f32)
    gemm3_mfma<64, true, false><<<782, 256, 0, stream>>>(
        (const void*)h, Bt2, Bt2 + 8192, Bt2 + 16384, s2b,
        xl, xr, nullptr, out, musig, lnw, lnb, NND);
    aggr_l2<<<6250, 256, 0, stream>>>(rowptr, csrs, xl, xr, att2, b2, out);
}